// Round 3
// baseline (665.606 us; speedup 1.0000x reference)
//
#include <hip/hip_runtime.h>
#include <cstddef>

// Problem constants (from reference)
#define BB   16
#define HHY  128
#define WWX  256
#define CC   64
#define DDp  12
#define HOUT 1024
#define WOUT 2048

// ---------------------------------------------------------------------------
// Kernel 1: cost volume. cost[b,h,w,d] = sum_c |L[b,h,w,c] - R[b,h,w-d,c]|
// (zero-pad shift: w<d contributes sum_c |L|).
// Block = one (b,h) row, thread = w. 8-channel chunks staged in LDS (24 KB
// total -> 6 blocks/CU). LDS stride 12 floats: 12*w mod 32 has period 8 and
// covers all bank quads uniformly -> optimal for ds_read_b128.
// ---------------------------------------------------------------------------
#define CCH 8
#define LST 12

__global__ __launch_bounds__(256) void cost_volume_k(const float* __restrict__ L,
                                                     const float* __restrict__ R,
                                                     float* __restrict__ cost) {
  __shared__ float lsL[WWX * LST];
  __shared__ float lsR[WWX * LST];
  const int t = threadIdx.x;
  const int h = blockIdx.x;
  const int b = blockIdx.y;
  const size_t rowbase = ((size_t)(b * HHY + h)) * WWX;
  const float* Lrow = L + rowbase * CC;
  const float* Rrow = R + rowbase * CC;

  float acc[DDp];
#pragma unroll
  for (int d = 0; d < DDp; ++d) acc[d] = 0.f;

  for (int c0 = 0; c0 < CC; c0 += CCH) {
    __syncthreads();
#pragma unroll
    for (int j = 0; j < 2; ++j) {
      const int i = t + 256 * j;     // float4 id in [0,512)
      const int w = i >> 1;
      const int r4 = (i & 1) << 2;
      const size_t g = (size_t)w * CC + c0 + r4;
      *(float4*)(&lsL[w * LST + r4]) = *(const float4*)(Lrow + g);
      *(float4*)(&lsR[w * LST + r4]) = *(const float4*)(Rrow + g);
    }
    __syncthreads();

    float l[CCH];
#pragma unroll
    for (int k = 0; k < CCH / 4; ++k)
      ((float4*)l)[k] = *(const float4*)(&lsL[t * LST + 4 * k]);

    float sl = 0.f;
#pragma unroll
    for (int k = 0; k < CCH; ++k) sl += fabsf(l[k]);

#pragma unroll
    for (int d = 0; d < DDp; ++d) {
      if (t >= d) {
        const float* rp = &lsR[(t - d) * LST];
        float a = 0.f;
#pragma unroll
        for (int k = 0; k < CCH / 4; ++k) {
          const float4 r4 = *(const float4*)(rp + 4 * k);
          a += fabsf(l[4 * k + 0] - r4.x) + fabsf(l[4 * k + 1] - r4.y) +
               fabsf(l[4 * k + 2] - r4.z) + fabsf(l[4 * k + 3] - r4.w);
        }
        acc[d] += a;
      } else {
        acc[d] += sl;
      }
    }
  }

  float* cp = cost + (rowbase + t) * DDp;
#pragma unroll
  for (int d = 0; d < DDp; d += 4)
    *(float4*)(cp + d) = make_float4(acc[d], acc[d + 1], acc[d + 2], acc[d + 3]);
}

// ---------------------------------------------------------------------------
// conv0: 3x3x3 conv, CIN=1 -> COUT=4, layout [B,H,W,D] -> [B,H,W,D,4].
// Block = one (b,h) row, thread = w. Input rows are 12 floats/w -> flat
// contiguous LDS copy (stride 12 is bank-uniform). Weights (108 f) in LDS.
// ---------------------------------------------------------------------------
__global__ __launch_bounds__(256) void conv0_k(const float* __restrict__ x,
                                               const float* __restrict__ wt,
                                               const float* __restrict__ bs,
                                               float* __restrict__ y) {
  __shared__ float ls[WWX * DDp];   // 12 KB
  __shared__ float wls[108];
  const int w = threadIdx.x;
  const int h = blockIdx.x;
  const int b = blockIdx.y;

  if (w < 27) ((float4*)wls)[w] = ((const float4*)wt)[w];

  const float b0 = bs[0], b1 = bs[1], b2 = bs[2], b3 = bs[3];
  float acc[DDp][4];
#pragma unroll
  for (int d = 0; d < DDp; ++d) {
    acc[d][0] = b0; acc[d][1] = b1; acc[d][2] = b2; acc[d][3] = b3;
  }

#pragma unroll
  for (int kh = 0; kh < 3; ++kh) {
    const int hh = h + kh - 1;
    if (hh < 0 || hh >= HHY) continue;  // block-uniform

    __syncthreads();
    const float* xr = x + ((size_t)(b * HHY + hh) * WWX) * DDp;
#pragma unroll
    for (int j = 0; j < 3; ++j) {
      const int fi4 = w + 256 * j;      // < 768
      ((float4*)ls)[fi4] = ((const float4*)xr)[fi4];
    }
    __syncthreads();

#pragma unroll
    for (int kw = 0; kw < 3; ++kw) {
      const int lw = w + kw - 1;
      if (lw < 0 || lw >= WWX) continue;

      float v[DDp];
#pragma unroll
      for (int k = 0; k < 3; ++k)
        ((float4*)v)[k] = *(const float4*)(&ls[lw * DDp + 4 * k]);

      float wr[12];
      const int tap = (kh * 3 + kw) * 12;
#pragma unroll
      for (int i = 0; i < 3; ++i) {
        const float4 w4 = *(const float4*)(&wls[tap + 4 * i]);
        wr[4 * i] = w4.x; wr[4 * i + 1] = w4.y; wr[4 * i + 2] = w4.z; wr[4 * i + 3] = w4.w;
      }

#pragma unroll
      for (int kd = 0; kd < 3; ++kd)
#pragma unroll
        for (int d = 0; d < DDp; ++d) {
          const int vi = d + kd - 1;
          if (vi < 0 || vi >= DDp) continue;
#pragma unroll
          for (int co = 0; co < 4; ++co)
            acc[d][co] += v[vi] * wr[kd * 4 + co];
        }
    }
  }

  float ov[DDp * 4];
#pragma unroll
  for (int d = 0; d < DDp; ++d)
#pragma unroll
    for (int co = 0; co < 4; ++co) ov[d * 4 + co] = fmaxf(acc[d][co], 0.f);

  float* yp = y + ((size_t)(b * HHY + h) * WWX + w) * DDp * 4;
#pragma unroll
  for (int i = 0; i < DDp; ++i) ((float4*)yp)[i] = ((float4*)ov)[i];
}

// ---------------------------------------------------------------------------
// Mid/final conv3d 3x3x3, CIN=4, layout [B,H,W,D,4]. Block covers a w-tile of
// 128 with +/-1 halo staged in LDS (zero-filled at image edges -> no kw
// divergence). 256 threads = 128 w  x  2 d-halves (d 0-5 / 6-11). Weights in
// LDS, broadcast reads. FUSE_SM: COUT=1 final conv + softmax(-cost) +
// disparity regression -> pred[b,h,w] (d-halves exchange via LDS).
// ---------------------------------------------------------------------------
template <int COUT, bool RELU, bool FUSE_SM>
__global__ __launch_bounds__(256) void conv_mid_k(const float* __restrict__ x,
                                                  const float* __restrict__ wt,
                                                  const float* __restrict__ bs,
                                                  float* __restrict__ y) {
  constexpr int CIN = 4;
  constexpr int DC = DDp * CIN;            // 48
  constexpr int S  = DC + 4;               // 52: 52w mod 32 = 20w -> uniform banks
  constexpr int WT = 128;
  constexpr int WN = 27 * CIN * COUT;      // 432 or 108
  __shared__ float ls[(WT + 2) * S];       // 27040 B
  __shared__ float wls[WN];

  const int t = threadIdx.x;
  const int tw = t & (WT - 1);
  const int dh = t >> 7;                   // wave-uniform (2 waves per half)
  const int d0 = 6 * dh;
  const int wbase = blockIdx.x * WT;
  const int h = blockIdx.y;
  const int b = blockIdx.z;

  if (t < WN / 4) ((float4*)wls)[t] = ((const float4*)wt)[t];

  float acc[6][COUT];
#pragma unroll
  for (int co = 0; co < COUT; ++co) {
    const float bv = bs[co];
#pragma unroll
    for (int d = 0; d < 6; ++d) acc[d][co] = bv;
  }

#pragma unroll
  for (int kh = 0; kh < 3; ++kh) {
    const int hh = h + kh - 1;
    if (hh < 0 || hh >= HHY) continue;  // block-uniform (syncs stay uniform)

    __syncthreads();
    const float* xr = x + ((size_t)(b * HHY + hh) * WWX) * DC;
#pragma unroll
    for (int j = 0; j < 7; ++j) {
      const int fi4 = t + 256 * j;
      if (fi4 < (WT + 2) * DC / 4) {     // 1560
        const int ws = fi4 / (DC / 4);   // /12
        const int r4 = (fi4 - ws * (DC / 4)) * 4;
        const int wslot = wbase - 1 + ws;
        float4 v4 = make_float4(0.f, 0.f, 0.f, 0.f);
        if (wslot >= 0 && wslot < WWX)
          v4 = *(const float4*)(xr + (size_t)wslot * DC + r4);
        *(float4*)(&ls[ws * S + r4]) = v4;
      }
    }
    __syncthreads();

#pragma unroll
    for (int kw = 0; kw < 3; ++kw) {
      const float* lp = &ls[(tw + kw) * S];

      // v[vo] covers dd = d0-1+vo, vo in [0,8); OOB slots (dd=-1 / dd=12) = 0.
      float v[8][CIN];
#pragma unroll
      for (int vo = 0; vo < 8; ++vo) {
        bool valid = true;
        if (vo == 0) valid = (dh != 0);
        if (vo == 7) valid = (dh != 1);
        if (valid) {
          const float4 x4 = *(const float4*)(lp + (d0 - 1 + vo) * CIN);
          v[vo][0] = x4.x; v[vo][1] = x4.y; v[vo][2] = x4.z; v[vo][3] = x4.w;
        } else {
          v[vo][0] = v[vo][1] = v[vo][2] = v[vo][3] = 0.f;
        }
      }

      float wr[3 * CIN * COUT];
      const int tap = (kh * 3 + kw) * 3 * CIN * COUT;
#pragma unroll
      for (int i = 0; i < 3 * CIN * COUT / 4; ++i) {
        const float4 w4 = *(const float4*)(&wls[tap + 4 * i]);
        wr[4 * i] = w4.x; wr[4 * i + 1] = w4.y; wr[4 * i + 2] = w4.z; wr[4 * i + 3] = w4.w;
      }

#pragma unroll
      for (int kd = 0; kd < 3; ++kd)
#pragma unroll
        for (int d = 0; d < 6; ++d) {
          const int vo = d + kd;
#pragma unroll
          for (int ci = 0; ci < CIN; ++ci)
#pragma unroll
            for (int co = 0; co < COUT; ++co)
              acc[d][co] += v[vo][ci] * wr[(kd * CIN + ci) * COUT + co];
        }
    }
  }

  if (FUSE_SM) {
    // exchange halves via LDS (d-major [12][128] -> conflict-free), then
    // softmax(-cost) + disparity regression on dh==0 threads.
    __syncthreads();
    float* sm = ls;
#pragma unroll
    for (int d = 0; d < 6; ++d) sm[(d0 + d) * WT + tw] = acc[d][0];
    __syncthreads();
    if (dh == 0) {
      float c[DDp];
#pragma unroll
      for (int d = 0; d < DDp; ++d) c[d] = sm[d * WT + tw];
      float mn = c[0];
#pragma unroll
      for (int d = 1; d < DDp; ++d) mn = fminf(mn, c[d]);
      float s = 0.f, sw = 0.f;
#pragma unroll
      for (int d = 0; d < DDp; ++d) {
        const float e = __expf(mn - c[d]);
        s += e;
        sw += e * (float)d;
      }
      y[(size_t)(b * HHY + h) * WWX + wbase + tw] = sw / s;
    }
  } else {
    float ov[6 * COUT];
#pragma unroll
    for (int d = 0; d < 6; ++d)
#pragma unroll
      for (int co = 0; co < COUT; ++co) {
        float r = acc[d][co];
        if (RELU) r = fmaxf(r, 0.f);
        ov[d * COUT + co] = r;
      }
    float* yp = y + ((size_t)(b * HHY + h) * WWX + wbase + tw) * DC + d0 * CIN;
#pragma unroll
    for (int i = 0; i < 6 * COUT / 4; ++i)
      ((float4*)yp)[i] = ((float4*)ov)[i];
  }
}

// ---------------------------------------------------------------------------
// 8x bilinear upsample, 4 outputs per thread. A 4-aligned output group maps to
// exactly 2 input columns (x0,x0+1) and 2 rows -> 4 loads, 1 float4 store.
// jax half-pixel convention; edge renormalization == index clamp (degenerate
// taps give the border value exactly).
// ---------------------------------------------------------------------------
__global__ __launch_bounds__(256) void resize4_k(const float* __restrict__ pred,
                                                 float* __restrict__ out) {
  const int idx = blockIdx.x * 256 + threadIdx.x;   // group id, 8.39M total
  const int xg = idx & 511;
  const int y = (idx >> 9) & 1023;
  const int b = idx >> 19;

  const int parity = xg & 1;
  const int m = xg >> 1;
  const int x0 = m - 1 + parity;
  const int x0c = max(x0, 0);
  const int x1c = min(x0 + 1, WWX - 1);
  const float wx0 = (parity ? 0.0625f : 0.5625f);

  const int py = y & 7;
  const int my = y >> 3;
  const int y0 = my - 1 + (py >= 4 ? 1 : 0);
  const float wy = (py >= 4) ? 0.0625f + (py - 4) * 0.125f : 0.5625f + py * 0.125f;
  const int y0c = max(y0, 0);
  const int y1c = min(y0 + 1, HHY - 1);

  const float* pb = pred + (size_t)b * HHY * WWX;
  const float a = pb[y0c * WWX + x0c];
  const float bv = pb[y0c * WWX + x1c];
  const float c = pb[y1c * WWX + x0c];
  const float d = pb[y1c * WWX + x1c];

  const float top0 = a + (bv - a) * wx0;
  const float bot0 = c + (d - c) * wx0;
  const float dtop = (bv - a) * 0.125f;
  const float dbot = (d - c) * 0.125f;

  float4 o;
  o.x = (top0) + wy * ((bot0) - (top0));
  o.y = (top0 + dtop) + wy * ((bot0 + dbot) - (top0 + dtop));
  o.z = (top0 + 2.f * dtop) + wy * ((bot0 + 2.f * dbot) - (top0 + 2.f * dtop));
  o.w = (top0 + 3.f * dtop) + wy * ((bot0 + 3.f * dbot) - (top0 + 3.f * dtop));

  *(float4*)(out + (size_t)idx * 4) = o;
}

// ---------------------------------------------------------------------------
extern "C" void kernel_launch(void* const* d_in, const int* in_sizes, int n_in,
                              void* d_out, int out_size, void* d_ws, size_t ws_size,
                              hipStream_t stream) {
  const float* feat_l = (const float*)d_in[0];
  const float* feat_r = (const float*)d_in[1];
  const float* w0 = (const float*)d_in[2];
  const float* b0 = (const float*)d_in[3];
  const float* w1 = (const float*)d_in[4];
  const float* b1 = (const float*)d_in[5];
  const float* w2 = (const float*)d_in[6];
  const float* b2 = (const float*)d_in[7];
  const float* w3 = (const float*)d_in[8];
  const float* b3 = (const float*)d_in[9];
  const float* wf = (const float*)d_in[10];
  const float* bf = (const float*)d_in[11];
  float* out = (float*)d_out;

  char* ws = (char*)d_ws;
  const size_t buf_bytes = (size_t)BB * HHY * WWX * DDp * 4 * sizeof(float);
  float* bufA = (float*)ws;
  float* bufB = (float*)(ws + buf_bytes);

  dim3 blk(256);
  dim3 grid_row(HHY, BB);            // row kernels
  dim3 grid_tile(2, HHY, BB);        // w-tiled conv kernels

  cost_volume_k<<<grid_row, blk, 0, stream>>>(feat_l, feat_r, bufA);
  conv0_k<<<grid_row, blk, 0, stream>>>(bufA, w0, b0, bufB);
  conv_mid_k<4, true, false><<<grid_tile, blk, 0, stream>>>(bufB, w1, b1, bufA);
  conv_mid_k<4, true, false><<<grid_tile, blk, 0, stream>>>(bufA, w2, b2, bufB);
  conv_mid_k<4, true, false><<<grid_tile, blk, 0, stream>>>(bufB, w3, b3, bufA);
  conv_mid_k<1, false, true><<<grid_tile, blk, 0, stream>>>(bufA, wf, bf, bufB);

  const int ngroups = BB * HOUT * (WOUT / 4);
  resize4_k<<<dim3(ngroups / 256), blk, 0, stream>>>(bufB, out);
}